// Round 2
// baseline (276.663 us; speedup 1.0000x reference)
//
#include <hip/hip_runtime.h>

// GraphPool: out[r] = max(feat[r], max_j feat[adj_d[i][j]]) per degree segment.
// N_PER=20000 rows/segment, degrees 0..10, F=128 fp32 (512B rows, cache-line aligned).
//
// R1 counters: 123us, FETCH 323MB / WRITE 110MB @3.6TB/s, VALUBusy 12%.
// This round: non-temporal self-load + store (protect L2 for gathers) and
// compile-time-degree unrolled bodies (all gathers in flight before one wait).

#define N_PER 20000
#define NDEG 10
#define F 128
#define N_ATOMS (N_PER * (NDEG + 1))
#define ROWS_PER_BLOCK 8   // 256 thr / 32 lanes-per-row; 20000%8==0 -> deg uniform per block

typedef float f4 __attribute__((ext_vector_type(4)));

struct AdjPtrs { const int* p[NDEG]; };

template<int DEG>
__device__ __forceinline__ f4 pool_deg(const float* __restrict__ feat,
                                       const int* __restrict__ a,
                                       f4 v, int lane)
{
    int idx[DEG];
    #pragma unroll
    for (int j = 0; j < DEG; ++j) idx[j] = a[j];          // same addr across 32 lanes -> broadcast
    f4 g[DEG];
    #pragma unroll
    for (int j = 0; j < DEG; ++j)                         // all gathers issue before any use
        g[j] = ((const f4*)(feat + (size_t)idx[j] * F))[lane];
    #pragma unroll
    for (int j = 0; j < DEG; ++j)
        v = __builtin_elementwise_max(v, g[j]);
    return v;
}

__global__ __launch_bounds__(256) void graphpool_kernel(
    const float* __restrict__ feat,
    AdjPtrs adj,
    float* __restrict__ out)
{
    const int row  = blockIdx.x * ROWS_PER_BLOCK + (threadIdx.x >> 5);
    const int lane = threadIdx.x & 31;
    const int deg  = row / N_PER;                         // block-uniform
    const int i    = row - deg * N_PER;

    // Self row: streaming, read-once -> non-temporal (don't evict gather lines).
    f4 v = __builtin_nontemporal_load((const f4*)(feat + (size_t)row * F) + lane);

    switch (deg) {                                        // block-uniform branch
    case 0: break;
    case 1:  v = pool_deg<1 >(feat, adj.p[0] + (size_t)i * 1,  v, lane); break;
    case 2:  v = pool_deg<2 >(feat, adj.p[1] + (size_t)i * 2,  v, lane); break;
    case 3:  v = pool_deg<3 >(feat, adj.p[2] + (size_t)i * 3,  v, lane); break;
    case 4:  v = pool_deg<4 >(feat, adj.p[3] + (size_t)i * 4,  v, lane); break;
    case 5:  v = pool_deg<5 >(feat, adj.p[4] + (size_t)i * 5,  v, lane); break;
    case 6:  v = pool_deg<6 >(feat, adj.p[5] + (size_t)i * 6,  v, lane); break;
    case 7:  v = pool_deg<7 >(feat, adj.p[6] + (size_t)i * 7,  v, lane); break;
    case 8:  v = pool_deg<8 >(feat, adj.p[7] + (size_t)i * 8,  v, lane); break;
    case 9:  v = pool_deg<9 >(feat, adj.p[8] + (size_t)i * 9,  v, lane); break;
    case 10: v = pool_deg<10>(feat, adj.p[9] + (size_t)i * 10, v, lane); break;
    }

    // Output: write-once stream -> non-temporal.
    __builtin_nontemporal_store(v, (f4*)(out + (size_t)row * F) + lane);
}

extern "C" void kernel_launch(void* const* d_in, const int* in_sizes, int n_in,
                              void* d_out, int out_size, void* d_ws, size_t ws_size,
                              hipStream_t stream) {
    const float* feat = (const float*)d_in[0];
    // d_in[1] = deg_slice (unused; layout fixed: start = deg*N_PER, count = N_PER)
    AdjPtrs adj;
    for (int d = 0; d < NDEG; ++d) adj.p[d] = (const int*)d_in[2 + d];
    float* out = (float*)d_out;

    const int grid = N_ATOMS / ROWS_PER_BLOCK;  // 27500 blocks, exact
    graphpool_kernel<<<grid, 256, 0, stream>>>(feat, adj, out);
}